// Round 8
// baseline (1428.506 us; speedup 1.0000x reference)
//
#include <hip/hip_runtime.h>

// Sizes
#define T 70
#define B 64
#define E 512
#define H 512
#define V 10000
#define NP 10112            // V padded to 79*128 rows in Whi/Wlo
#define TB (T*B)            // 4480
#define SLOT (H*B)          // 32768 floats per (t) state slot
#define LOGITS_N (T*B*V)    // 44800000

// chain_hyb weight partition (per 256-k half, per layer):
//   k-offsets [0,56)   -> VGPR   (28 float4/thread pinned, 112 VGPR, 229 KB/layer)
//   k-offsets [56,94)  -> LDS    (38 rows x 512 n x 2 halves = 155.6 KB)
//   k-offsets [94,256) -> stream (81 float4/thread/step, 663 KB/layer)
// Round-7 lesson: 40 pinned float4 (160 regs) made total demand ~230/256 and the
// allocator spilled ALL pins to scratch (VGPR_Count=116) -> scratch re-read from
// L2 every step. 28 float4 leaves a wide margin so the pins actually stick.
#define WV_F 57344          // floats in VGPR section  (2*28*256 float4)
#define WL_F 38912          // floats in LDS section   (2*38*512)
#define WS_F4 41472         // float4 in stream section (2*81*256)
#define WLAYER 262144       // floats per layer (1 MB)

typedef __attribute__((ext_vector_type(8))) short bh8;   // 8 bf16 (4 VGPRs)
typedef __attribute__((ext_vector_type(4))) float f32x4; // MFMA accumulator

__device__ __forceinline__ float ftanh(float x) {
    // tanh(x) = 1 - 2/(exp(2x)+1); saturates correctly at +/-inf
    float e = __expf(2.0f * x);
    return 1.0f - 2.0f / (e + 1.0f);
}

__device__ __forceinline__ unsigned short f2bf(float x) {  // RNE fp32->bf16
    unsigned int u = __float_as_uint(x);
    u += 0x7FFFu + ((u >> 16) & 1u);
    return (unsigned short)(u >> 16);
}
__device__ __forceinline__ float bf2f(unsigned short h) {
    return __uint_as_float(((unsigned int)h) << 16);
}

// ---------------------------------------------------------------------------
// 1) Embedding gather: X[t][b][e] (row-major) = emb_table[ids[t][b]][e]
// ---------------------------------------------------------------------------
__global__ __launch_bounds__(256) void gather_emb(const int* __restrict__ ids,
                                                  const float* __restrict__ emb,
                                                  float* __restrict__ X) {
    int i = blockIdx.x * 256 + threadIdx.x;       // float4 index
    if (i >= TB * (E / 4)) return;
    int tok = i >> 7;                             // E/4 = 128 float4 per token
    int e4 = i & 127;
    int id = ids[tok];
    ((float4*)X)[i] = ((const float4*)emb)[id * 128 + e4];
}

// ---------------------------------------------------------------------------
// 2) One-time pack of the recurrent weight halves W{0,1}[n][512+k] into the
//    three chain_hyb sections (all destinations linear for L2 streaming):
//    Wv: [hq][j2<28][n2] float4 {W(n0,k),W(n1,k),W(n0,k+1),W(n1,k+1)}, k=hq*256+2*j2
//    Ws: [hq][j2s<81][n2] float4, k = hq*256+94+2*j2s
//    Wl: [hq][jr<38][n]  float,  k = hq*256+56+jr
// ---------------------------------------------------------------------------
__global__ __launch_bounds__(256) void pack_w(const float* __restrict__ W0,
                                              const float* __restrict__ W1,
                                              float* __restrict__ Wpk) {
    int g = blockIdx.x * 256 + threadIdx.x;       // [0, 189440)
    int l = g >= 94720;
    int u = g - l * 94720;
    const float* S = l ? W1 : W0;
    float* D = Wpk + l * WLAYER;

    if (u < 14336) {                              // Wv float4 units
        int n2 = u & 255, q = u >> 8;             // q in [0,56) = hq*28 + j2
        int j2 = q % 28, hq = q / 28;
        int k = hq * 256 + 2 * j2;
        int n0 = 2 * n2;
        float2 r0 = *(const float2*)(S + (size_t)n0 * 1024 + 512 + k);
        float2 r1 = *(const float2*)(S + (size_t)(n0 + 1) * 1024 + 512 + k);
        ((float4*)D)[(hq * 28 + j2) * 256 + n2] = make_float4(r0.x, r1.x, r0.y, r1.y);
    } else if (u < 14336 + WS_F4) {               // Ws float4 units
        int v = u - 14336;
        int n2 = v & 255, q = v >> 8;             // q in [0,162) = hq*81 + j2s
        int j2s = q % 81, hq = q / 81;
        int k = hq * 256 + 94 + 2 * j2s;
        int n0 = 2 * n2;
        float2 r0 = *(const float2*)(S + (size_t)n0 * 1024 + 512 + k);
        float2 r1 = *(const float2*)(S + (size_t)(n0 + 1) * 1024 + 512 + k);
        ((float4*)D)[(WV_F + WL_F) / 4 + (hq * 81 + j2s) * 256 + n2] =
            make_float4(r0.x, r1.x, r0.y, r1.y);
    } else {                                      // Wl scalar units
        int w = u - (14336 + WS_F4);              // [0, 38912)
        int n = w & 511, q = w >> 9;              // q in [0,76) = hq*38 + jr
        int jr = q % 38, hq = q / 38;
        int k = hq * 256 + 56 + jr;
        D[WV_F + (hq * 38 + jr) * 512 + n] = S[(size_t)n * 1024 + 512 + k];
    }
}

// ---------------------------------------------------------------------------
// 2b) One-time split of Wout (fp32 [V][512]) into bf16 hi/lo, zero-padded to
//     [NP][512] rows.
// ---------------------------------------------------------------------------
__global__ __launch_bounds__(256) void split_w(const float* __restrict__ Wout,
                                               unsigned short* __restrict__ Whi,
                                               unsigned short* __restrict__ Wlo) {
    int i = blockIdx.x * 256 + threadIdx.x;       // [0, NP*512)
    if (i >= NP * 512) return;
    int v = i >> 9;
    float x = (v < V) ? Wout[i] : 0.f;
    unsigned short hi = f2bf(x);
    Whi[i] = hi;
    Wlo[i] = f2bf(x - bf2f(hi));
}

// ---------------------------------------------------------------------------
// 3) P0 = X @ W0x.T + b0   -> layout (T, B=64, N=512)  [n contiguous]
// ---------------------------------------------------------------------------
__global__ __launch_bounds__(256) void gemm_p0(const float* __restrict__ X,
                                               const float* __restrict__ W0,
                                               const float* __restrict__ b0v,
                                               float* __restrict__ P0) {
    __shared__ float As[32][68];   // [k][b]
    __shared__ float Ws[32][68];   // [k][n]
    int t = blockIdx.y;
    int n0 = blockIdx.x * 64;
    int tid = threadIdx.x;
    int bq = tid & 15;    // b block = bq*4
    int nq = tid >> 4;    // n local = nq*4
    const float* A = X + t * 64 * E;
    float acc[4][4] = {{0.f}};     // [b][n]

    for (int kc = 0; kc < 512; kc += 32) {
        for (int i = tid; i < 512; i += 256) {
            int bb = i >> 3, kq = i & 7;
            float4 a = *(const float4*)(A + bb * E + kc + kq * 4);
            As[kq*4+0][bb] = a.x; As[kq*4+1][bb] = a.y;
            As[kq*4+2][bb] = a.z; As[kq*4+3][bb] = a.w;
        }
        for (int i = tid; i < 512; i += 256) {
            int nn = i >> 3, kq = i & 7;
            float4 w = *(const float4*)(W0 + (size_t)(n0 + nn) * 1024 + kc + kq * 4);
            Ws[kq*4+0][nn] = w.x; Ws[kq*4+1][nn] = w.y;
            Ws[kq*4+2][nn] = w.z; Ws[kq*4+3][nn] = w.w;
        }
        __syncthreads();
#pragma unroll
        for (int kk = 0; kk < 32; kk++) {
            float4 a = *(const float4*)&As[kk][bq * 4];
            float4 w = *(const float4*)&Ws[kk][nq * 4];
            acc[0][0] += a.x*w.x; acc[0][1] += a.x*w.y; acc[0][2] += a.x*w.z; acc[0][3] += a.x*w.w;
            acc[1][0] += a.y*w.x; acc[1][1] += a.y*w.y; acc[1][2] += a.y*w.z; acc[1][3] += a.y*w.w;
            acc[2][0] += a.z*w.x; acc[2][1] += a.z*w.y; acc[2][2] += a.z*w.z; acc[2][3] += a.z*w.w;
            acc[3][0] += a.w*w.x; acc[3][1] += a.w*w.y; acc[3][2] += a.w*w.z; acc[3][3] += a.w*w.w;
        }
        __syncthreads();
    }
    int nb = n0 + nq * 4;
    float4 bo = *(const float4*)(b0v + nb);
#pragma unroll
    for (int i = 0; i < 4; i++) {
        int bb = bq * 4 + i;
        float4 r = make_float4(acc[i][0] + bo.x, acc[i][1] + bo.y,
                               acc[i][2] + bo.z, acc[i][3] + bo.w);
        *(float4*)(P0 + (size_t)t * SLOT + bb * 512 + nb) = r;
    }
}

// ---------------------------------------------------------------------------
// 3b) P1 = H0 @ W1x.T + b1  -> layout (T, B, N).  A rows are length 512.
// ---------------------------------------------------------------------------
__global__ __launch_bounds__(256) void gemm_p1(const float* __restrict__ H0,
                                               const float* __restrict__ W1,
                                               const float* __restrict__ b1v,
                                               float* __restrict__ P1) {
    __shared__ float As[32][68];   // [k][b]
    __shared__ float Ws[32][68];   // [k][n]
    int t = blockIdx.y;
    int n0 = blockIdx.x * 64;
    int tid = threadIdx.x;
    int bq = tid & 15;
    int nq = tid >> 4;
    const float* A = H0 + (size_t)t * SLOT;
    float acc[4][4] = {{0.f}};     // [b][n]

    for (int kc = 0; kc < 512; kc += 32) {
        for (int i = tid; i < 512; i += 256) {
            int bb = i >> 3, kq = i & 7;
            float4 a = *(const float4*)(A + bb * 512 + kc + kq * 4);
            As[kq*4+0][bb] = a.x; As[kq*4+1][bb] = a.y;
            As[kq*4+2][bb] = a.z; As[kq*4+3][bb] = a.w;
        }
        for (int i = tid; i < 512; i += 256) {
            int nn = i >> 3, kq = i & 7;
            float4 w = *(const float4*)(W1 + (size_t)(n0 + nn) * 1024 + kc + kq * 4);
            Ws[kq*4+0][nn] = w.x; Ws[kq*4+1][nn] = w.y;
            Ws[kq*4+2][nn] = w.z; Ws[kq*4+3][nn] = w.w;
        }
        __syncthreads();
#pragma unroll
        for (int kk = 0; kk < 32; kk++) {
            float4 a = *(const float4*)&As[kk][bq * 4];
            float4 w = *(const float4*)&Ws[kk][nq * 4];
            acc[0][0] += a.x*w.x; acc[0][1] += a.x*w.y; acc[0][2] += a.x*w.z; acc[0][3] += a.x*w.w;
            acc[1][0] += a.y*w.x; acc[1][1] += a.y*w.y; acc[1][2] += a.y*w.z; acc[1][3] += a.y*w.w;
            acc[2][0] += a.z*w.x; acc[2][1] += a.z*w.y; acc[2][2] += a.z*w.z; acc[2][3] += a.z*w.w;
            acc[3][0] += a.w*w.x; acc[3][1] += a.w*w.y; acc[3][2] += a.w*w.z; acc[3][3] += a.w*w.w;
        }
        __syncthreads();
    }
    int nb = n0 + nq * 4;
    float4 bo = *(const float4*)(b1v + nb);
#pragma unroll
    for (int i = 0; i < 4; i++) {
        int bb = bq * 4 + i;
        float4 r = make_float4(acc[i][0] + bo.x, acc[i][1] + bo.y,
                               acc[i][2] + bo.z, acc[i][3] + bo.w);
        *(float4*)(P1 + (size_t)t * SLOT + bb * 512 + nb) = r;
    }
}

// ---------------------------------------------------------------------------
// 4) Hybrid-resident single-layer recurrence. 28 pinned float4 (112 VGPR,
//    wide margin below the 256 cap so they actually stay resident),
//    155.6 KB LDS weights, 663 KB/step streamed from L2.
// ---------------------------------------------------------------------------
#define RPT28(X) X(0) X(1) X(2) X(3) X(4) X(5) X(6) X(7) X(8) X(9) X(10) X(11) \
  X(12) X(13) X(14) X(15) X(16) X(17) X(18) X(19) X(20) X(21) X(22) X(23) \
  X(24) X(25) X(26) X(27)
#define RPT14P(X) X(0,0,1) X(1,2,3) X(2,4,5) X(3,6,7) X(4,8,9) X(5,10,11) \
  X(6,12,13) X(7,14,15) X(8,16,17) X(9,18,19) X(10,20,21) X(11,22,23) \
  X(12,24,25) X(13,26,27)

__global__ __launch_bounds__(512, 2) void chain_hyb(const float* __restrict__ P,
                                                    const float* __restrict__ hidden,
                                                    const float* __restrict__ Wp,
                                                    float* __restrict__ Hist,
                                                    unsigned short* __restrict__ Hhi,
                                                    unsigned short* __restrict__ Hlo,
                                                    float* __restrict__ out,
                                                    int layer) {
    __shared__ float lds_w[WL_F];     // 155.6 KB: [hq][jr][n]
    __shared__ float hs[512];
    __shared__ float2 part2[256];
    int tid = threadIdx.x;
    int b   = blockIdx.x;
    int n2  = tid & 255;
    int hq  = tid >> 8;               // wave-uniform
    int n0  = 2 * n2;

    // ---- one-time: VGPR section into 28 NAMED float4 registers ----
    const float4* wv = (const float4*)Wp + hq * (28 * 256) + n2;
#define DECLW(i) float4 w##i = wv[(i) * 256];
    RPT28(DECLW)
#undef DECLW

    // ---- one-time: LDS section ----
    {
        const float4* wl4 = (const float4*)(Wp + WV_F);
        float4* l4 = (float4*)lds_w;
        for (int i = tid; i < WL_F / 4; i += 512) l4[i] = wl4[i];
    }
    hs[tid & 511] = hidden[layer * SLOT + b * 512 + (tid & 511)];

    // pin: asm may modify the values, so loads can't be sunk into the loop
#define PINW(i) asm volatile("" : "+v"(w##i.x), "+v"(w##i.y), "+v"(w##i.z), "+v"(w##i.w));
    RPT28(PINW)
#undef PINW
    __syncthreads();

    const float4* wsp = (const float4*)(Wp + WV_F + WL_F) + hq * (81 * 256) + n2;
    const float4* hs4 = (const float4*)hs;
    const float2* ldsw2 = (const float2*)lds_w;
    int hql4 = hq * 64;               // hs4 base for this k-half
    int klb  = hq * 256 + 56;         // hs base for LDS section
    int ksb  = hq * 256 + 94;         // hs base for streamed section

    for (int s = 0; s < T; s++) {
        float2 pin = make_float2(0.f, 0.f);
        if (hq == 0)
            pin = *(const float2*)(P + (size_t)s * SLOT + b * 512 + n0);

        float ax = 0.f, ay = 0.f;

        // streamed section first: loads issue early, FMAs below hide latency
#pragma unroll 8
        for (int j = 0; j < 81; j++) {
            float4 wv4 = wsp[j * 256];
            float2 h2 = *(const float2*)&hs[ksb + 2 * j];
            ax += wv4.x * h2.x + wv4.z * h2.y;
            ay += wv4.y * h2.x + wv4.w * h2.y;
        }

        // VGPR-resident section (no memory traffic): k = hq*256 + [0,56)
#define FMAV(m, A, B2) { float4 h4 = hs4[hql4 + (m)]; \
        ax += w##A.x * h4.x + w##A.z * h4.y + w##B2.x * h4.z + w##B2.z * h4.w; \
        ay += w##A.y * h4.x + w##A.w * h4.y + w##B2.y * h4.z + w##B2.w * h4.w; }
        RPT14P(FMAV)
#undef FMAV

        // LDS-resident section: k = hq*256 + [56,94), 19 row-pairs
#pragma unroll
        for (int g = 0; g < 19; g++) {
            float2 h2 = *(const float2*)&hs[klb + 2 * g];
            float2 l0 = ldsw2[(hq * 38 + 2 * g) * 256 + n2];
            float2 l1 = ldsw2[(hq * 38 + 2 * g + 1) * 256 + n2];
            ax += l0.x * h2.x + l1.x * h2.y;
            ay += l0.y * h2.x + l1.y * h2.y;
        }

        if (hq) part2[n2] = make_float2(ax, ay);
        __syncthreads();
        if (hq == 0) {
            float2 pr = part2[n2];
            float o0 = ftanh(pin.x + ax + pr.x);
            float o1 = ftanh(pin.y + ay + pr.y);
            hs[n0] = o0; hs[n0 + 1] = o1;
            if (layer == 0) {
                *(float2*)(Hist + (size_t)s * SLOT + b * 512 + n0) = make_float2(o0, o1);
            } else {
                size_t m = (size_t)(s * 64 + b) * 512 + n0;
                unsigned short h0 = f2bf(o0), h1 = f2bf(o1);
                Hhi[m] = h0;     Hhi[m + 1] = h1;
                Hlo[m] = f2bf(o0 - bf2f(h0));
                Hlo[m + 1] = f2bf(o1 - bf2f(h1));
            }
        }
        __syncthreads();
    }

    // final hidden -> d_out tail, (L,B,H) row-major
    out[LOGITS_N + layer * SLOT + b * 512 + tid] = hs[tid];
}

// ---------------------------------------------------------------------------
// 5) logits = tanh(H1 @ Wout.T + bout) via split-bf16 MFMA.
//    256(M) x 256(N) tile, 512 threads = 8 waves in a 2(M) x 4(N) grid;
//    each wave owns 128 rows x 64 cols = 8x4 frags of mfma_f32_16x16x32_bf16.
//    Halves operand re-fetch vs the 128x128 tile (1.45 GB -> 0.74 GB).
//    B rows >= NP guarded to zero in staging; A over-reads (m >= TB) land in
//    adjacent workspace (safe) and stores are guarded (TB is 16-aligned).
// ---------------------------------------------------------------------------
__global__ __launch_bounds__(512, 2) void logits_mfma(const unsigned short* __restrict__ Ahi,
                                                      const unsigned short* __restrict__ Alo,
                                                      const unsigned short* __restrict__ Whi,
                                                      const unsigned short* __restrict__ Wlo,
                                                      const float* __restrict__ boutv,
                                                      float* __restrict__ out) {
    __shared__ unsigned short Ah[256 * 40], Al[256 * 40];
    __shared__ unsigned short Bh[256 * 40], Bl[256 * 40];
    int tid = threadIdx.x;
    int v0 = blockIdx.x * 256;
    int mb = blockIdx.y * 256;
    int lane = tid & 63;
    int wid = tid >> 6;          // 0..7
    int lr = lane & 15;
    int lg = lane >> 4;
    int wm = wid & 1;            // M half (128 rows)
    int wn = wid >> 1;           // N quarter (64 cols)

    f32x4 acc[8][4];             // [mf][nf]
#pragma unroll
    for (int i = 0; i < 8; i++)
#pragma unroll
        for (int j = 0; j < 4; j++) {
            acc[i][j][0] = 0.f; acc[i][j][1] = 0.f;
            acc[i][j][2] = 0.f; acc[i][j][3] = 0.f;
        }

    int aoff[8], boff[4];
#pragma unroll
    for (int f = 0; f < 8; f++) aoff[f] = (wm * 128 + f * 16 + lr) * 40 + lg * 8;
#pragma unroll
    for (int f = 0; f < 4; f++) boff[f] = (wn * 64 + f * 16 + lr) * 40 + lg * 8;

    const uint4 z4 = make_uint4(0u, 0u, 0u, 0u);

    for (int kb = 0; kb < 512; kb += 32) {
        // stage 256x32 of A(hi,lo) and B(hi,lo): 2048+2048 uint4, 8/thread
#pragma unroll
        for (int it = 0; it < 2; ++it) {
            int idx = it * 512 + tid;        // [0,1024): r = row, u = k-octet
            int r = idx >> 2, u = idx & 3;
            int d = r * 40 + u * 8;
            size_t sA = (size_t)(mb + r) * 512 + kb + u * 8;
            *(uint4*)&Ah[d] = *(const uint4*)&Ahi[sA];
            *(uint4*)&Al[d] = *(const uint4*)&Alo[sA];
            int rB = v0 + r;
            size_t sB = (size_t)rB * 512 + kb + u * 8;
            bool okB = rB < NP;
            *(uint4*)&Bh[d] = okB ? *(const uint4*)&Whi[sB] : z4;
            *(uint4*)&Bl[d] = okB ? *(const uint4*)&Wlo[sB] : z4;
        }
        __syncthreads();

        bh8 bhf[4], blf[4];
#pragma unroll
        for (int nf = 0; nf < 4; nf++) {
            bhf[nf] = *(const bh8*)&Bh[boff[nf]];
            blf[nf] = *(const bh8*)&Bl[boff[nf]];
        }
#pragma unroll
        for (int mf = 0; mf < 8; mf++) {
            bh8 ah = *(const bh8*)&Ah[aoff[mf]];
            bh8 al = *(const bh8*)&Al[aoff[mf]];
#pragma unroll
            for (int nf = 0; nf < 4; nf++) {
                acc[mf][nf] = __builtin_amdgcn_mfma_f32_16x16x32_bf16(ah, bhf[nf], acc[mf][nf], 0, 0, 0);
                acc[mf][nf] = __builtin_amdgcn_mfma_f32_16x16x32_bf16(ah, blf[nf], acc[mf][nf], 0, 0, 0);
                acc[mf][nf] = __builtin_amdgcn_mfma_f32_16x16x32_bf16(al, bhf[nf], acc[mf][nf], 0, 0, 0);
            }
        }
        __syncthreads();
    }

    // epilogue: D col = lane&15, row = (lane>>4)*4 + reg
#pragma unroll
    for (int nf = 0; nf < 4; nf++) {
        int v = v0 + wn * 64 + nf * 16 + lr;
        if (v < V) {
            float bo = boutv[v];
#pragma unroll
            for (int mf = 0; mf < 8; mf++) {
                int gmb = mb + wm * 128 + mf * 16;     // 16-aligned; TB is 16-aligned
                if (gmb < TB) {
                    int gm = gmb + lg * 4;
#pragma unroll
                    for (int reg = 0; reg < 4; reg++)
                        out[(size_t)(gm + reg) * V + v] = ftanh(acc[mf][nf][reg] + bo);
                }
            }
        }
    }
}

// ---------------------------------------------------------------------------
extern "C" void kernel_launch(void* const* d_in, const int* in_sizes, int n_in,
                              void* d_out, int out_size, void* d_ws, size_t ws_size,
                              hipStream_t stream) {
    const int*   ids    = (const int*)d_in[0];
    const float* hidden = (const float*)d_in[1];
    const float* emb    = (const float*)d_in[2];
    const float* W0     = (const float*)d_in[3];
    const float* b0v    = (const float*)d_in[4];
    const float* W1     = (const float*)d_in[5];
    const float* b1v    = (const float*)d_in[6];
    const float* Wout   = (const float*)d_in[7];
    const float* boutv  = (const float*)d_in[8];
    float* out = (float*)d_out;
    float* ws  = (float*)d_ws;

    // layout (floats):
    //   X    [0,        2293760)   later overlaid by P1
    //   P0   [2293760,  4587520)   later overlaid by H1hi/H1lo (bf16)
    //   H0   [4587520,  6881280)
    //   Wpk  [6881280,  7405568)
    //   Whi  [7405568,  9994240)   NP*512 ushort
    //   Wlo  [9994240, 12582912)   NP*512 ushort    total 50.3 MB
    float* X    = ws;
    float* P0   = ws + 2293760;
    float* H0   = ws + 4587520;
    float* Wpk  = ws + 6881280;
    float* P1   = X;
    unsigned short* H1hi = (unsigned short*)(ws + 2293760);
    unsigned short* H1lo = (unsigned short*)(ws + 2293760 + 1146880);
    unsigned short* Whi  = (unsigned short*)(ws + 7405568);
    unsigned short* Wlo  = (unsigned short*)(ws + 9994240);

    gather_emb<<<2240, 256, 0, stream>>>(ids, emb, X);
    pack_w<<<740, 256, 0, stream>>>(W0, W1, Wpk);
    split_w<<<(NP * 512) / 256, 256, 0, stream>>>(Wout, Whi, Wlo);
    gemm_p0<<<dim3(8, T), 256, 0, stream>>>(X, W0, b0v, P0);
    chain_hyb<<<64, 512, 0, stream>>>(P0, hidden, Wpk, H0, nullptr, nullptr, out, 0);
    gemm_p1<<<dim3(8, T), 256, 0, stream>>>(H0, W1, b1v, P1);
    chain_hyb<<<64, 512, 0, stream>>>(P1, hidden, Wpk + WLAYER, nullptr, H1hi, H1lo, out, 1);
    logits_mfma<<<dim3((NP + 255) / 256, (TB + 255) / 256), 512, 0, stream>>>(H1hi, H1lo, Whi, Wlo, boutv, out);
}